// Round 3
// baseline (83.185 us; speedup 1.0000x reference)
//
#include <hip/hip_runtime.h>
#include <cmath>

#define T_LEN 8192
#define B_ROWS 128
#define ND 360          // MAX_DELAY - MIN_DELAY
#define MIN_DELAY_C 60
#define BLOCK 512

// Recursive-doubling comb filter:  (1+P) y = x,  P = a1 z^dA + a2 z^dB.
// (1+P)(1-P)(1+P^2)(1+P^4) = 1-P^8  =>
//   u = (1+P^4)(1+P^2)(1-P) x   (3 parallel FIR passes)
//   (1-P^8) y = u               (9-tap IIR, min lag 8*min(dA,dB) >= 488
//                                -> only ceil(8192/488)=17 serial chunks)
__global__ __launch_bounds__(BLOCK) void ks_resonator_kernel(
    const float* __restrict__ excitation,     // (128,1,8192)
    const float* __restrict__ gumbel,         // (360,)
    const float* __restrict__ delay_param,    // (360,)
    const float* __restrict__ feedback_gain,  // (1,)
    const float* __restrict__ refl,           // (2,)
    float* __restrict__ out)                  // (128,1,8192)
{
    __shared__ float A[T_LEN];    // 32 KB
    __shared__ float Bv[T_LEN];   // 32 KB  (ping-pong)

    const int tid  = threadIdx.x;
    const int lane = tid & 63;
    const int row  = blockIdx.x;

    // ---- per-wave argmax over (delay_param + gumbel); every wave computes the
    //      same answer redundantly -> no cross-wave reduction needed ----
    float best = -INFINITY; int bi = 0;
    for (int i = lane; i < ND; i += 64) {
        float v = delay_param[i] + gumbel[i];
        if (v > best) { best = v; bi = i; }   // strict '>' keeps first occurrence
    }
    #pragma unroll
    for (int off = 32; off > 0; off >>= 1) {
        float v2 = __shfl_xor(best, off);
        int   i2 = __shfl_xor(bi,   off);
        if (v2 > best || (v2 == best && i2 < bi)) { best = v2; bi = i2; }
    }
    const int p = bi;

    // ---- coefficients (uniform, redundant per thread) ----
    float k1 = tanhf(tanhf(refl[0]));
    float k2 = tanhf(tanhf(refl[1]));
    float a1 = k1 * (1.0f - k2);
    float a2 = fminf(fmaxf(k2, -0.999f), 0.999f);
    float bnd = 0.999f - fabsf(a2);
    a1 = fminf(fmaxf(a1, -bnd), bnd);
    float g = powf(1.0f / (1.0f + expf(-feedback_gain[0])), 0.45f);
    a1 *= g; a2 *= g;

    const int dA = MIN_DELAY_C + p + 1;             // tap delays of P
    const int dB = MIN_DELAY_C + ((p + 1) % ND) + 1;

    // ---- load row -> A (float4 coalesced) ----
    const float4* xv = (const float4*)(excitation + (size_t)row * T_LEN);
    float4* Av4 = (float4*)A;
    #pragma unroll
    for (int i = 0; i < T_LEN / 4 / BLOCK; i++)
        Av4[i * BLOCK + tid] = xv[i * BLOCK + tid];
    __syncthreads();

    // ---- pass 1: B = (1 - P) A ----
    {
        const float c0 = -a1, c1 = -a2;
        for (int t = tid; t < T_LEN; t += BLOCK) {
            float s = A[t];
            if (t >= dA) s += c0 * A[t - dA];
            if (t >= dB) s += c1 * A[t - dB];
            Bv[t] = s;
        }
    }
    __syncthreads();

    // ---- pass 2: A = (1 + P^2) B ----
    {
        const float c0 = a1 * a1, c1 = 2.f * a1 * a2, c2 = a2 * a2;
        const int  d0 = 2 * dA,  d1 = dA + dB,       d2 = 2 * dB;
        for (int t = tid; t < T_LEN; t += BLOCK) {
            float s = Bv[t];
            if (t >= d0) s += c0 * Bv[t - d0];
            if (t >= d1) s += c1 * Bv[t - d1];
            if (t >= d2) s += c2 * Bv[t - d2];
            A[t] = s;
        }
    }
    __syncthreads();

    // ---- pass 3: B = (1 + P^4) A ----
    {
        const float a1_2 = a1 * a1, a2_2 = a2 * a2;
        const float c0 = a1_2 * a1_2, c1 = 4.f * a1_2 * a1 * a2,
                    c2 = 6.f * a1_2 * a2_2, c3 = 4.f * a1 * a2 * a2_2,
                    c4 = a2_2 * a2_2;
        const int d0 = 4 * dA, d1 = 3 * dA + dB, d2 = 2 * (dA + dB),
                  d3 = dA + 3 * dB, d4 = 4 * dB;
        for (int t = tid; t < T_LEN; t += BLOCK) {
            float s = A[t];
            if (t >= d0) s += c0 * A[t - d0];
            if (t >= d1) s += c1 * A[t - d1];
            if (t >= d2) s += c2 * A[t - d2];
            if (t >= d3) s += c3 * A[t - d3];
            if (t >= d4) s += c4 * A[t - d4];
            Bv[t] = s;
        }
    }
    __syncthreads();

    // ---- recurrence: (1 - P^8) y = B, in place on B.
    //      taps c[i] = C(8,i) a1^(8-i) a2^i at delay (8-i)dA + i*dB (all >= 8*min)
    {
        float c[9]; int d[9];
        const float binom[9] = {1.f, 8.f, 28.f, 56.f, 70.f, 56.f, 28.f, 8.f, 1.f};
        #pragma unroll
        for (int i = 0; i <= 8; i++) {
            float pa = 1.f, pb = 1.f;
            for (int j = 0; j < 8 - i; j++) pa *= a1;
            for (int j = 0; j < i; j++)     pb *= a2;
            c[i] = binom[i] * pa * pb;
            d[i] = (8 - i) * dA + i * dB;
        }
        const int chunk = 8 * (dA < dB ? dA : dB);   // >= 488
        for (int pos = 0; pos < T_LEN; pos += chunk) {
            int end = pos + chunk; if (end > T_LEN) end = T_LEN;
            for (int t = pos + tid; t < end; t += BLOCK) {
                float s = Bv[t];
                #pragma unroll
                for (int i = 0; i <= 8; i++)
                    if (t >= d[i]) s += c[i] * Bv[t - d[i]];
                Bv[t] = s;
            }
            __syncthreads();
        }
    }

    // ---- store (float4 coalesced) ----
    float4* ov = (float4*)(out + (size_t)row * T_LEN);
    const float4* Bv4 = (const float4*)Bv;
    #pragma unroll
    for (int i = 0; i < T_LEN / 4 / BLOCK; i++)
        ov[i * BLOCK + tid] = Bv4[i * BLOCK + tid];
}

extern "C" void kernel_launch(void* const* d_in, const int* in_sizes, int n_in,
                              void* d_out, int out_size, void* d_ws, size_t ws_size,
                              hipStream_t stream) {
    const float* excitation    = (const float*)d_in[0];
    const float* gumbel        = (const float*)d_in[1];
    const float* delay_param   = (const float*)d_in[2];
    const float* feedback_gain = (const float*)d_in[3];
    const float* refl          = (const float*)d_in[4];
    float* out = (float*)d_out;

    ks_resonator_kernel<<<B_ROWS, BLOCK, 0, stream>>>(
        excitation, gumbel, delay_param, feedback_gain, refl, out);
}